// Round 1
// baseline (377.791 us; speedup 1.0000x reference)
//
#include <hip/hip_runtime.h>
#include <hip/hip_bf16.h>
#include <math.h>

#define CCH 192
#define EPS 1e-5f

__device__ __constant__ int d_LOWX[32] = {0,0,1,1,0,2,2,1,2,0,3,4,0,1,3,0,1,2,3,4,5,0,1,2,3,4,5,6,1,2,3,4};
__device__ __constant__ int d_LOWY[32] = {0,1,0,1,2,0,1,2,2,3,0,0,4,3,1,5,4,3,2,1,0,6,5,4,3,2,1,0,6,5,4,3};

// ---------------- A1: gate conv for n=0 only, per-row partial sums ----------------
// grid 56 (h rows), block 256. partial[h*32+o] = sum_w relu(bn2(conv(x[0,:,h,w])))[o]
__global__ __launch_bounds__(256) void gate_conv_kernel(
    const float* __restrict__ x, const float* __restrict__ wg1,
    const float* __restrict__ bn2_g, const float* __restrict__ bn2_b,
    const float* __restrict__ bn2_m, const float* __restrict__ bn2_v,
    float* __restrict__ partial) {
  __shared__ float wls[32 * 192];       // 24 KB
  __shared__ float gbuf[4][32][64];     // 32 KB
  const int h = blockIdx.x;
  const int t = threadIdx.x;
  for (int i = t; i < 32 * 192; i += 256) wls[i] = wg1[i];
  __syncthreads();
  const int cq = t >> 6;   // 0..3, wave id -> channel quarter
  const int w  = t & 63;   // lane -> column (active < 56)
  float acc[32];
#pragma unroll
  for (int o = 0; o < 32; ++o) acc[o] = 0.f;
  const float* xrow = x + h * 56;  // n=0: x[c*3136 + h*56 + w]
  for (int c = cq * 48; c < cq * 48 + 48; ++c) {
    float xv = (w < 56) ? xrow[c * 3136 + w] : 0.f;
#pragma unroll
    for (int o = 0; o < 32; ++o) acc[o] += xv * wls[o * 192 + c];
  }
#pragma unroll
  for (int o = 0; o < 32; ++o) gbuf[cq][o][w] = acc[o];
  __syncthreads();
  // combine 4 channel-quarters, BN + ReLU (only w<56 entries)
  for (int e = t; e < 32 * 56; e += 256) {
    int o = e / 56, ww = e % 56;
    float v = gbuf[0][o][ww] + gbuf[1][o][ww] + gbuf[2][o][ww] + gbuf[3][o][ww];
    float sc = bn2_g[o] * rsqrtf(bn2_v[o] + EPS);
    v = v * sc + (bn2_b[o] - bn2_m[o] * sc);
    gbuf[0][o][ww] = fmaxf(v, 0.f);
  }
  __syncthreads();
  if (t < 32) {
    float s = 0.f;
    for (int ww = 0; ww < 56; ++ww) s += gbuf[0][t][ww];
    partial[h * 32 + t] = s;
  }
}

// ---------------- B1: reduce -> xg0 -> param -> filt; pack w1d center taps ----------------
// grid 1, block 256
__global__ __launch_bounds__(256) void mid_kernel(
    const float* __restrict__ partial, const float* __restrict__ wg2,
    const float* __restrict__ bg2, const float* __restrict__ beta,
    const float* __restrict__ w1d,
    float* __restrict__ filt, float* __restrict__ wt) {
  __shared__ float gm[32];
  __shared__ float xg[32];
  __shared__ float param[33];
  __shared__ float Btab[7][7];
  const int t = threadIdx.x;
  if (t < 32) {
    float s = 0.f;
    for (int hh = 0; hh < 56; ++hh) s += partial[hh * 32 + t];
    gm[t] = s * (1.f / 3136.f);
  }
  if (t < 49) {
    int f = t / 7, tt = t % 7;
    float r = cosf(3.14159265358979323846f * (float)f * ((float)tt + 0.5f) / 7.f) * rsqrtf(7.f);
    Btab[f][tt] = (f == 0) ? r : r * sqrtf(2.f);
  }
  __syncthreads();
  if (t < 32) {
    float a = bg2[t];
    for (int k = 0; k < 32; ++k) a += gm[k] * wg2[t * 32 + k];
    xg[t] = fmaxf(tanhf(a), 0.f) + beta[0];
  }
  __syncthreads();
  if (t == 0) {
    float s = 0.f;
    for (int k = 0; k < 32; ++k) s += xg[k];
    float psum = 0.f;
    param[0] = 0.f;
    for (int i = 0; i < 31; ++i) {
      float p = rintf(xg[i] / s * (float)CCH);  // nearest-even, matches jnp.round
      param[i + 1] = p;
      psum += p;
    }
    param[32] = (float)CCH - psum;
  }
  __syncthreads();
  for (int c = t; c < CCH; c += 256) {
    int bi = -1;
    float cf = (float)c;
    for (int i = 0; i < 32; ++i)
      if (cf >= param[i] && cf < param[i + 1]) bi = i;  // last match wins
    int fx = (bi >= 0) ? d_LOWX[bi] : 0;
    int fy = (bi >= 0) ? d_LOWY[bi] : 0;
    for (int cell = 0; cell < 49; ++cell) {
      int a = cell / 7, b = cell % 7;
      float v = (bi >= 0) ? Btab[fx][a] * Btab[fy][b] : 0.f;
      filt[c * 49 + cell] = v;
    }
  }
  // wt[k*192 + c] = w1d[c][k][1]  (coalesced consumer layout)
  for (int i = t; i < CCH * CCH; i += 256) {
    int k = i / CCH, c = i % CCH;
    wt[i] = w1d[c * (CCH * 3) + 3 * k + 1];
  }
}

// ---------------- A2: fused pool*filt over all n,c -> y[n][c] ----------------
// grid 64*48, block 256 (4 waves, one channel per wave)
__global__ __launch_bounds__(256) void pool_kernel(
    const float* __restrict__ x, const float* __restrict__ filt,
    float* __restrict__ yvec) {
  __shared__ float fl[4 * 49];
  const int blk = blockIdx.x;
  const int n = blk / 48, g = blk % 48;
  const int t = threadIdx.x, wv = t >> 6, lane = t & 63;
  const int c0 = g * 4;
  if (t < 196) fl[t] = filt[c0 * 49 + t];
  __syncthreads();
  const int c = c0 + wv;
  const float4* xp = (const float4*)(x + (size_t)(n * CCH + c) * 3136);
  float acc = 0.f;
#pragma unroll
  for (int it = 0; it < 13; ++it) {
    int f = it * 64 + lane;          // float4 index 0..783
    if (f < 784) {
      float4 v = xp[f];
      int hh = f / 14;               // row 0..55
      int wq = f - hh * 14;          // float4-col 0..13
      int cell = (hh >> 3) * 7 + (wq >> 1);
      acc += (v.x + v.y + v.z + v.w) * fl[wv * 49 + cell];
    }
  }
  acc *= (1.f / 64.f);
#pragma unroll
  for (int d = 32; d > 0; d >>= 1) acc += __shfl_xor(acc, d, 64);
  if (lane == 0) yvec[n * CCH + c] = acc;
}

// ---------------- B2: y @ w1d_center^T + b1d -> BN1 -> ReLU -> scale = 1+v ----------------
// grid 64 (n), block 256
__global__ __launch_bounds__(256) void out_scale_kernel(
    const float* __restrict__ yvec, const float* __restrict__ wt,
    const float* __restrict__ b1d, const float* __restrict__ bn1_g,
    const float* __restrict__ bn1_b, const float* __restrict__ bn1_m,
    const float* __restrict__ bn1_v, float* __restrict__ scale) {
  __shared__ float yl[CCH];
  const int n = blockIdx.x, t = threadIdx.x;
  if (t < CCH) yl[t] = yvec[n * CCH + t];
  __syncthreads();
  if (t < CCH) {
    float acc = b1d[t];
    for (int k = 0; k < CCH; ++k) acc += yl[k] * wt[k * CCH + t];
    float sc = bn1_g[t] * rsqrtf(bn1_v[t] + EPS);
    float v = (acc - bn1_m[t]) * sc + bn1_b[t];
    scale[n * CCH + t] = 1.f + fmaxf(v, 0.f);
  }
}

// ---------------- C: out = x * scale[n,c] ----------------
// one float4 per thread; grid 37632, block 256
__global__ __launch_bounds__(256) void apply_kernel(
    const float* __restrict__ x, const float* __restrict__ scale,
    float* __restrict__ out) {
  const int f = blockIdx.x * 256 + threadIdx.x;   // float4 index < 9,633,792
  const int nc = f / 784;                          // 3136/4 floats4 per (n,c)
  const float s = scale[nc];
  float4 v = ((const float4*)x)[f];
  v.x *= s; v.y *= s; v.z *= s; v.w *= s;
  ((float4*)out)[f] = v;
}

extern "C" void kernel_launch(void* const* d_in, const int* in_sizes, int n_in,
                              void* d_out, int out_size, void* d_ws, size_t ws_size,
                              hipStream_t stream) {
  const float* x     = (const float*)d_in[0];
  const float* wg1   = (const float*)d_in[1];
  const float* bn2_g = (const float*)d_in[2];
  const float* bn2_b = (const float*)d_in[3];
  const float* bn2_m = (const float*)d_in[4];
  const float* bn2_v = (const float*)d_in[5];
  const float* wg2   = (const float*)d_in[6];
  const float* bg2   = (const float*)d_in[7];
  const float* beta  = (const float*)d_in[8];
  const float* w1d   = (const float*)d_in[9];
  const float* b1d   = (const float*)d_in[10];
  const float* bn1_g = (const float*)d_in[11];
  const float* bn1_b = (const float*)d_in[12];
  const float* bn1_m = (const float*)d_in[13];
  const float* bn1_v = (const float*)d_in[14];
  float* out = (float*)d_out;

  float* ws      = (float*)d_ws;
  float* partial = ws;                   // 56*32   = 1792
  float* filt    = partial + 1792;       // 192*49  = 9408
  float* wt      = filt + 9408;          // 192*192 = 36864
  float* yvec    = wt + 36864;           // 64*192  = 12288
  float* scale   = yvec + 12288;         // 64*192  = 12288

  gate_conv_kernel<<<56, 256, 0, stream>>>(x, wg1, bn2_g, bn2_b, bn2_m, bn2_v, partial);
  mid_kernel<<<1, 256, 0, stream>>>(partial, wg2, bg2, beta, w1d, filt, wt);
  pool_kernel<<<64 * 48, 256, 0, stream>>>(x, filt, yvec);
  out_scale_kernel<<<64, 256, 0, stream>>>(yvec, wt, b1d, bn1_g, bn1_b, bn1_m, bn1_v, scale);
  apply_kernel<<<37632, 256, 0, stream>>>(x, scale, out);
}

// Round 2
// 361.524 us; speedup vs baseline: 1.0450x; 1.0450x over previous
//
#include <hip/hip_runtime.h>
#include <hip/hip_bf16.h>
#include <math.h>

#define CCH 192
#define EPS 1e-5f

__device__ __constant__ int d_LOWX[32] = {0,0,1,1,0,2,2,1,2,0,3,4,0,1,3,0,1,2,3,4,5,0,1,2,3,4,5,6,1,2,3,4};
__device__ __constant__ int d_LOWY[32] = {0,1,0,1,2,0,1,2,2,3,0,0,4,3,1,5,4,3,2,1,0,6,5,4,3,2,1,0,6,5,4,3};

// ---------------- P: pack w1d center taps, parallel transpose ----------------
// wt[k*192 + c] = w1d[c][k][1]; grid 144, block 256 (exactly 36864 threads)
__global__ __launch_bounds__(256) void pack_wt_kernel(
    const float* __restrict__ w1d, float* __restrict__ wt) {
  const int i = blockIdx.x * 256 + threadIdx.x;  // < 36864
  const int c = i / CCH, k = i - c * CCH;
  wt[k * CCH + c] = w1d[c * (CCH * 3) + 3 * k + 1];
}

// ---------------- A1: gate conv for n=0 only, per-row partial sums ----------------
// grid 56 (h rows), block 256. partial[h*32+o] = sum_w relu(bn2(conv(x[0,:,h,w])))[o]
// wg1 indexed wave-uniformly -> compiler emits s_load (scalar pipe), no LDS staging.
__global__ __launch_bounds__(256) void gate_conv_kernel(
    const float* __restrict__ x, const float* __restrict__ wg1,
    const float* __restrict__ bn2_g, const float* __restrict__ bn2_b,
    const float* __restrict__ bn2_m, const float* __restrict__ bn2_v,
    float* __restrict__ partial) {
  __shared__ float gbuf[4][32][64];     // 32 KB
  const int h = blockIdx.x;
  const int t = threadIdx.x;
  const int cq = t >> 6;   // 0..3, wave id -> channel quarter
  const int w  = t & 63;   // lane -> column (active < 56)
  float acc[32];
#pragma unroll
  for (int o = 0; o < 32; ++o) acc[o] = 0.f;
  const float* xrow = x + h * 56;  // n=0: x[c*3136 + h*56 + w]
  for (int c = cq * 48; c < cq * 48 + 48; ++c) {
    float xv = (w < 56) ? xrow[c * 3136 + w] : 0.f;
#pragma unroll
    for (int o = 0; o < 32; ++o) acc[o] += xv * wg1[o * 192 + c];  // uniform -> s_load
  }
#pragma unroll
  for (int o = 0; o < 32; ++o) gbuf[cq][o][w] = acc[o];
  __syncthreads();
  // combine 4 channel-quarters, BN + ReLU (only w<56 entries)
  for (int e = t; e < 32 * 56; e += 256) {
    int o = e / 56, ww = e % 56;
    float v = gbuf[0][o][ww] + gbuf[1][o][ww] + gbuf[2][o][ww] + gbuf[3][o][ww];
    float sc = bn2_g[o] * rsqrtf(bn2_v[o] + EPS);
    v = v * sc + (bn2_b[o] - bn2_m[o] * sc);
    gbuf[0][o][ww] = fmaxf(v, 0.f);
  }
  __syncthreads();
  if (t < 32) {
    float s = 0.f;
    for (int ww = 0; ww < 56; ++ww) s += gbuf[0][t][ww];
    partial[h * 32 + t] = s;
  }
}

// ---------------- B1: reduce -> xg0 -> param -> filt ----------------
// grid 1, block 256 (now tiny: no wt packing)
__global__ __launch_bounds__(256) void mid_kernel(
    const float* __restrict__ partial, const float* __restrict__ wg2,
    const float* __restrict__ bg2, const float* __restrict__ beta,
    float* __restrict__ filt) {
  __shared__ float gm[32];
  __shared__ float xg[32];
  __shared__ float param[33];
  __shared__ float Btab[7][7];
  const int t = threadIdx.x;
  if (t < 32) {
    float s = 0.f;
    for (int hh = 0; hh < 56; ++hh) s += partial[hh * 32 + t];
    gm[t] = s * (1.f / 3136.f);
  }
  if (t < 49) {
    int f = t / 7, tt = t % 7;
    float r = cosf(3.14159265358979323846f * (float)f * ((float)tt + 0.5f) / 7.f) * rsqrtf(7.f);
    Btab[f][tt] = (f == 0) ? r : r * sqrtf(2.f);
  }
  __syncthreads();
  if (t < 32) {
    float a = bg2[t];
    for (int k = 0; k < 32; ++k) a += gm[k] * wg2[t * 32 + k];
    xg[t] = fmaxf(tanhf(a), 0.f) + beta[0];
  }
  __syncthreads();
  if (t == 0) {
    float s = 0.f;
    for (int k = 0; k < 32; ++k) s += xg[k];
    float psum = 0.f;
    param[0] = 0.f;
    for (int i = 0; i < 31; ++i) {
      float p = rintf(xg[i] / s * (float)CCH);  // nearest-even, matches jnp.round
      param[i + 1] = p;
      psum += p;
    }
    param[32] = (float)CCH - psum;
  }
  __syncthreads();
  for (int c = t; c < CCH; c += 256) {
    int bi = -1;
    float cf = (float)c;
    for (int i = 0; i < 32; ++i)
      if (cf >= param[i] && cf < param[i + 1]) bi = i;  // last match wins
    int fx = (bi >= 0) ? d_LOWX[bi] : 0;
    int fy = (bi >= 0) ? d_LOWY[bi] : 0;
    for (int cell = 0; cell < 49; ++cell) {
      int a = cell / 7, b = cell % 7;
      float v = (bi >= 0) ? Btab[fx][a] * Btab[fy][b] : 0.f;
      filt[c * 49 + cell] = v;
    }
  }
}

// ---------------- A2: fused pool*filt over all n,c -> y[n][c] ----------------
// grid 64*48, block 256 (4 waves, one channel per wave)
__global__ __launch_bounds__(256) void pool_kernel(
    const float* __restrict__ x, const float* __restrict__ filt,
    float* __restrict__ yvec) {
  __shared__ float fl[4 * 49];
  const int blk = blockIdx.x;
  const int n = blk / 48, g = blk % 48;
  const int t = threadIdx.x, wv = t >> 6, lane = t & 63;
  const int c0 = g * 4;
  if (t < 196) fl[t] = filt[c0 * 49 + t];
  __syncthreads();
  const int c = c0 + wv;
  const float4* xp = (const float4*)(x + (size_t)(n * CCH + c) * 3136);
  float acc = 0.f;
#pragma unroll
  for (int it = 0; it < 13; ++it) {
    int f = it * 64 + lane;          // float4 index 0..783
    if (f < 784) {
      float4 v = xp[f];
      int hh = f / 14;               // row 0..55
      int wq = f - hh * 14;          // float4-col 0..13
      int cell = (hh >> 3) * 7 + (wq >> 1);
      acc += (v.x + v.y + v.z + v.w) * fl[wv * 49 + cell];
    }
  }
  acc *= (1.f / 64.f);
#pragma unroll
  for (int d = 32; d > 0; d >>= 1) acc += __shfl_xor(acc, d, 64);
  if (lane == 0) yvec[n * CCH + c] = acc;
}

// ---------------- B2: y @ w1d_center^T + b1d -> BN1 -> ReLU -> scale = 1+v ----------------
// grid 64 (n), block 256
__global__ __launch_bounds__(256) void out_scale_kernel(
    const float* __restrict__ yvec, const float* __restrict__ wt,
    const float* __restrict__ b1d, const float* __restrict__ bn1_g,
    const float* __restrict__ bn1_b, const float* __restrict__ bn1_m,
    const float* __restrict__ bn1_v, float* __restrict__ scale) {
  __shared__ float yl[CCH];
  const int n = blockIdx.x, t = threadIdx.x;
  if (t < CCH) yl[t] = yvec[n * CCH + t];
  __syncthreads();
  if (t < CCH) {
    float acc = b1d[t];
    for (int k = 0; k < CCH; ++k) acc += yl[k] * wt[k * CCH + t];
    float sc = bn1_g[t] * rsqrtf(bn1_v[t] + EPS);
    float v = (acc - bn1_m[t]) * sc + bn1_b[t];
    scale[n * CCH + t] = 1.f + fmaxf(v, 0.f);
  }
}

// ---------------- C: out = x * scale[n,c] ----------------
// one float4 per thread; grid 37632, block 256
__global__ __launch_bounds__(256) void apply_kernel(
    const float* __restrict__ x, const float* __restrict__ scale,
    float* __restrict__ out) {
  const int f = blockIdx.x * 256 + threadIdx.x;   // float4 index < 9,633,792
  const int nc = f / 784;                          // 3136/4 float4s per (n,c)
  const float s = scale[nc];
  float4 v = ((const float4*)x)[f];
  v.x *= s; v.y *= s; v.z *= s; v.w *= s;
  ((float4*)out)[f] = v;
}

extern "C" void kernel_launch(void* const* d_in, const int* in_sizes, int n_in,
                              void* d_out, int out_size, void* d_ws, size_t ws_size,
                              hipStream_t stream) {
  const float* x     = (const float*)d_in[0];
  const float* wg1   = (const float*)d_in[1];
  const float* bn2_g = (const float*)d_in[2];
  const float* bn2_b = (const float*)d_in[3];
  const float* bn2_m = (const float*)d_in[4];
  const float* bn2_v = (const float*)d_in[5];
  const float* wg2   = (const float*)d_in[6];
  const float* bg2   = (const float*)d_in[7];
  const float* beta  = (const float*)d_in[8];
  const float* w1d   = (const float*)d_in[9];
  const float* b1d   = (const float*)d_in[10];
  const float* bn1_g = (const float*)d_in[11];
  const float* bn1_b = (const float*)d_in[12];
  const float* bn1_m = (const float*)d_in[13];
  const float* bn1_v = (const float*)d_in[14];
  float* out = (float*)d_out;

  float* ws      = (float*)d_ws;
  float* partial = ws;                   // 56*32   = 1792
  float* filt    = partial + 1792;       // 192*49  = 9408
  float* wt      = filt + 9408;          // 192*192 = 36864
  float* yvec    = wt + 36864;           // 64*192  = 12288
  float* scale   = yvec + 12288;         // 64*192  = 12288

  pack_wt_kernel<<<144, 256, 0, stream>>>(w1d, wt);   // no deps on gate chain
  gate_conv_kernel<<<56, 256, 0, stream>>>(x, wg1, bn2_g, bn2_b, bn2_m, bn2_v, partial);
  mid_kernel<<<1, 256, 0, stream>>>(partial, wg2, bg2, beta, filt);
  pool_kernel<<<64 * 48, 256, 0, stream>>>(x, filt, yvec);
  out_scale_kernel<<<64, 256, 0, stream>>>(yvec, wt, b1d, bn1_g, bn1_b, bn1_m, bn1_v, scale);
  apply_kernel<<<37632, 256, 0, stream>>>(x, scale, out);
}

// Round 4
// 358.483 us; speedup vs baseline: 1.0539x; 1.0085x over previous
//
#include <hip/hip_runtime.h>
#include <hip/hip_bf16.h>
#include <math.h>

#define CCH 192
#define EPS 1e-5f

typedef float vfloat4 __attribute__((ext_vector_type(4)));  // clang-native: OK for nontemporal builtins

__device__ __constant__ int d_LOWX[32] = {0,0,1,1,0,2,2,1,2,0,3,4,0,1,3,0,1,2,3,4,5,0,1,2,3,4,5,6,1,2,3,4};
__device__ __constant__ int d_LOWY[32] = {0,1,0,1,2,0,1,2,2,3,0,0,4,3,1,5,4,3,2,1,0,6,5,4,3,2,1,0,6,5,4,3};

// ---------------- K1: fused pre-pass, one launch, three block roles ----------------
//  blocks [0,3072):   unweighted adaptive pool  x -> xp[n][c][49]   (filt-INdependent)
//  blocks [3072,3216): pack wt[k*192+c] = w1d[c][k][1]
//  blocks [3216,3272): gate conv rows for n=0 -> partial[h][32]  (bit-identical to passing ver)
__global__ __launch_bounds__(256) void fused_pre_kernel(
    const float* __restrict__ x, const float* __restrict__ w1d,
    const float* __restrict__ wg1,
    const float* __restrict__ bn2_g, const float* __restrict__ bn2_b,
    const float* __restrict__ bn2_m, const float* __restrict__ bn2_v,
    float* __restrict__ xp, float* __restrict__ wt, float* __restrict__ partial) {
  __shared__ float smem[4 * 32 * 64];   // 32 KB: gbuf for gate role, 196 floats for pool role
  const int b = blockIdx.x;
  const int t = threadIdx.x;
  if (b < 3072) {
    // ---- pool role: 4 waves, one channel per wave, perfectly coalesced float4 reads
    const int n = b / 48, g = b % 48;
    const int wv = t >> 6, lane = t & 63;
    const int c0 = g * 4, c = c0 + wv;
    if (t < 196) smem[t] = 0.f;         // cellsum[4][49]
    __syncthreads();
    const vfloat4* xv = (const vfloat4*)(x + (size_t)(n * CCH + c) * 3136);
#pragma unroll
    for (int it = 0; it < 13; ++it) {
      int f = it * 64 + lane;           // float4 index 0..783
      if (f < 784) {
        vfloat4 v = xv[f];
        int hh = f / 14;                // image row 0..55
        int wq = f - hh * 14;           // float4-col 0..13
        int cell = (hh >> 3) * 7 + (wq >> 1);
        atomicAdd(&smem[wv * 49 + cell], v.x + v.y + v.z + v.w);  // ds_add_f32
      }
    }
    __syncthreads();
    if (t < 196) xp[((size_t)n * CCH + c0) * 49 + t] = smem[t] * (1.f / 64.f);
  } else if (b < 3216) {
    // ---- pack role
    const int i = (b - 3072) * 256 + t;           // < 36864
    const int c = i / CCH, k = i - c * CCH;
    wt[k * CCH + c] = w1d[c * (CCH * 3) + 3 * k + 1];
  } else {
    // ---- gate role: one h row, all 192 channels (n=0 only)
    const int h = b - 3216;
    const int cq = t >> 6;
    const int w  = t & 63;
    float acc[32];
#pragma unroll
    for (int o = 0; o < 32; ++o) acc[o] = 0.f;
    const float* xrow = x + h * 56;               // x[c*3136 + h*56 + w]
    for (int c = cq * 48; c < cq * 48 + 48; ++c) {
      float xvv = (w < 56) ? xrow[c * 3136 + w] : 0.f;
#pragma unroll
      for (int o = 0; o < 32; ++o) acc[o] += xvv * wg1[o * 192 + c];  // uniform -> s_load
    }
#pragma unroll
    for (int o = 0; o < 32; ++o) smem[(cq * 32 + o) * 64 + w] = acc[o];
    __syncthreads();
    for (int e = t; e < 32 * 56; e += 256) {
      int o = e / 56, ww = e % 56;
      float v = smem[(0 * 32 + o) * 64 + ww] + smem[(1 * 32 + o) * 64 + ww] +
                smem[(2 * 32 + o) * 64 + ww] + smem[(3 * 32 + o) * 64 + ww];
      float sc = bn2_g[o] * rsqrtf(bn2_v[o] + EPS);
      v = v * sc + (bn2_b[o] - bn2_m[o] * sc);
      smem[o * 64 + ww] = fmaxf(v, 0.f);
    }
    __syncthreads();
    if (t < 32) {
      float s = 0.f;
      for (int ww = 0; ww < 56; ++ww) s += smem[t * 64 + ww];
      partial[h * 32 + t] = s;
    }
  }
}

// ---------------- K2: reduce -> xg0 -> param -> filt (1 block) ----------------
__global__ __launch_bounds__(256) void mid_kernel(
    const float* __restrict__ partial, const float* __restrict__ wg2,
    const float* __restrict__ bg2, const float* __restrict__ beta,
    float* __restrict__ filt) {
  __shared__ float gm[32];
  __shared__ float xg[32];
  __shared__ float param[33];
  __shared__ float Btab[7][7];
  const int t = threadIdx.x;
  if (t < 32) {
    float s = 0.f;
    for (int hh = 0; hh < 56; ++hh) s += partial[hh * 32 + t];
    gm[t] = s * (1.f / 3136.f);
  }
  if (t < 49) {
    int f = t / 7, tt = t % 7;
    float r = cosf(3.14159265358979323846f * (float)f * ((float)tt + 0.5f) / 7.f) * rsqrtf(7.f);
    Btab[f][tt] = (f == 0) ? r : r * sqrtf(2.f);
  }
  __syncthreads();
  if (t < 32) {
    float a = bg2[t];
    for (int k = 0; k < 32; ++k) a += gm[k] * wg2[t * 32 + k];
    xg[t] = fmaxf(tanhf(a), 0.f) + beta[0];
  }
  __syncthreads();
  if (t == 0) {
    float s = 0.f;
    for (int k = 0; k < 32; ++k) s += xg[k];
    float psum = 0.f;
    param[0] = 0.f;
    for (int i = 0; i < 31; ++i) {
      float p = rintf(xg[i] / s * (float)CCH);  // nearest-even, matches jnp.round
      param[i + 1] = p;
      psum += p;
    }
    param[32] = (float)CCH - psum;
  }
  __syncthreads();
  for (int c = t; c < CCH; c += 256) {
    int bi = -1;
    float cf = (float)c;
    for (int i = 0; i < 32; ++i)
      if (cf >= param[i] && cf < param[i + 1]) bi = i;  // last match wins
    int fx = (bi >= 0) ? d_LOWX[bi] : 0;
    int fy = (bi >= 0) ? d_LOWY[bi] : 0;
    for (int cell = 0; cell < 49; ++cell) {
      int a = cell / 7, bb = cell % 7;
      float v = (bi >= 0) ? Btab[fx][a] * Btab[fy][bb] : 0.f;
      filt[c * 49 + cell] = v;
    }
  }
}

// ---------------- K3: yvec = sum(xp*filt) -> GEMV -> BN1 -> ReLU -> scale ----------------
// grid 64 (n), block 256 (192 active)
__global__ __launch_bounds__(256) void gemv_scale_kernel(
    const float* __restrict__ xp, const float* __restrict__ filt,
    const float* __restrict__ wt, const float* __restrict__ b1d,
    const float* __restrict__ bn1_g, const float* __restrict__ bn1_b,
    const float* __restrict__ bn1_m, const float* __restrict__ bn1_v,
    float* __restrict__ scale) {
  __shared__ float yl[CCH];
  const int n = blockIdx.x, t = threadIdx.x;
  if (t < CCH) {
    const float* xc = xp + ((size_t)n * CCH + t) * 49;
    const float* fc = filt + t * 49;
    float s = 0.f;
#pragma unroll
    for (int cell = 0; cell < 49; ++cell) s += xc[cell] * fc[cell];
    yl[t] = s;
  }
  __syncthreads();
  if (t < CCH) {
    float acc = b1d[t];
    for (int k = 0; k < CCH; ++k) acc += yl[k] * wt[k * CCH + t];
    float sc = bn1_g[t] * rsqrtf(bn1_v[t] + EPS);
    float v = (acc - bn1_m[t]) * sc + bn1_b[t];
    scale[n * CCH + t] = 1.f + fmaxf(v, 0.f);
  }
}

// ---------------- K4: out = x * scale[n,c]; nontemporal store keeps x in L3 ----------------
__global__ __launch_bounds__(256) void apply_kernel(
    const float* __restrict__ x, const float* __restrict__ scale,
    float* __restrict__ out) {
  const int f = blockIdx.x * 256 + threadIdx.x;   // float4 index < 9,633,792
  const int nc = f / 784;                          // 3136/4 float4s per (n,c)
  const float s = scale[nc];
  vfloat4 v = __builtin_nontemporal_load(((const vfloat4*)x) + f);
  v *= s;
  __builtin_nontemporal_store(v, ((vfloat4*)out) + f);
}

extern "C" void kernel_launch(void* const* d_in, const int* in_sizes, int n_in,
                              void* d_out, int out_size, void* d_ws, size_t ws_size,
                              hipStream_t stream) {
  const float* x     = (const float*)d_in[0];
  const float* wg1   = (const float*)d_in[1];
  const float* bn2_g = (const float*)d_in[2];
  const float* bn2_b = (const float*)d_in[3];
  const float* bn2_m = (const float*)d_in[4];
  const float* bn2_v = (const float*)d_in[5];
  const float* wg2   = (const float*)d_in[6];
  const float* bg2   = (const float*)d_in[7];
  const float* beta  = (const float*)d_in[8];
  const float* w1d   = (const float*)d_in[9];
  const float* b1d   = (const float*)d_in[10];
  const float* bn1_g = (const float*)d_in[11];
  const float* bn1_b = (const float*)d_in[12];
  const float* bn1_m = (const float*)d_in[13];
  const float* bn1_v = (const float*)d_in[14];
  float* out = (float*)d_out;

  float* ws      = (float*)d_ws;
  float* partial = ws;                   // 56*32      = 1792
  float* filt    = partial + 1792;       // 192*49     = 9408
  float* wt      = filt + 9408;          // 192*192    = 36864
  float* xp      = wt + 36864;           // 64*192*49  = 602112
  float* scale   = xp + 602112;          // 64*192     = 12288

  fused_pre_kernel<<<3272, 256, 0, stream>>>(x, w1d, wg1, bn2_g, bn2_b, bn2_m, bn2_v,
                                             xp, wt, partial);
  mid_kernel<<<1, 256, 0, stream>>>(partial, wg2, bg2, beta, filt);
  gemv_scale_kernel<<<64, 256, 0, stream>>>(xp, filt, wt, b1d, bn1_g, bn1_b, bn1_m, bn1_v, scale);
  apply_kernel<<<37632, 256, 0, stream>>>(x, scale, out);
}